// Round 1
// baseline (117.585 us; speedup 1.0000x reference)
//
#include <hip/hip_runtime.h>

// Problem constants (fixed by the reference)
#define BATCH   8192
#define GROUPS  512
#define ARITY   3
#define OUT_DIM 16
#define NV      27          // 3^3 vertices
#define XCOLS   (GROUPS*ARITY)      // 1536
#define OCOLS   (GROUPS*OUT_DIM)    // 8192

// Tiling: block = 256 threads = 4 waves.
//   wave w handles 16 groups; lane = (g_local<<2)|oq computes out[., g*16 + oq*4 .. +4)
//   block covers 64 groups (blockIdx.y) x 64 batches (blockIdx.x)
#define BTILE 64
#define GTILE 64
#define XTILE_F4 ( (BTILE * GTILE * ARITY) / 4 )   // 3072 float4 = 48 KiB

__global__ __launch_bounds__(256) void lattice_interp_kernel(
    const float* __restrict__ X,
    const float* __restrict__ P,
    float* __restrict__ out)
{
    __shared__ float xs[BTILE * GTILE * ARITY];   // 48 KiB, linear layout

    const int t  = threadIdx.x;
    const int b0 = blockIdx.x * BTILE;
    const int gb = blockIdx.y * GTILE;

    // ---- stage X tile rows [b0,b0+64) cols [gb*3, gb*3+192) into LDS.
    // flat float4 index f = t + k*256 ; r = f/48, c = f%48 ;
    // LDS dest offset = f*16B  (linear => matches global_load_lds lane layout)
    {
        const float* src_base = X + (size_t)b0 * XCOLS + gb * ARITY;
        #pragma unroll
        for (int k = 0; k < 12; ++k) {
            const int f = t + k * 256;
            const int r = f / 48;
            const int c = f % 48;
            const float* src = src_base + (size_t)r * XCOLS + c * 4;
            __builtin_amdgcn_global_load_lds(
                (const __attribute__((address_space(1))) void*)src,
                (__attribute__((address_space(3))) void*)&xs[f * 4],
                16, 0, 0);
        }
    }

    // ---- load this lane's param slice into registers (27 x float4), reused
    // for all 64 batches: no per-batch param traffic.
    const int wave = t >> 6;
    const int lane = t & 63;
    const int gl   = wave * 16 + (lane >> 2);   // group-local within block, 0..63
    const int oq   = lane & 3;                  // which float4 of the 16 outputs
    const int g    = gb + gl;

    float4 p[NV];
    {
        const float4* P4 = reinterpret_cast<const float4*>(P) + (size_t)g * (NV * 4) + oq;
        #pragma unroll
        for (int v = 0; v < NV; ++v) p[v] = P4[v * 4];
    }

    __syncthreads();   // drains the global_load_lds (compiler emits vmcnt(0))

    // ---- batch loop: all lanes of a wave share b; stores are one contiguous
    // 1 KiB segment per wave per b (lane l -> base + 4*l floats).
    const int xcol = gl * ARITY;
    float* out_base = out + (size_t)b0 * OCOLS + gb * OUT_DIM + t * 4;

    #pragma unroll 1
    for (int b = 0; b < BTILE; ++b) {
        const float x0 = xs[b * (GTILE * ARITY) + xcol + 0];
        const float x1 = xs[b * (GTILE * ARITY) + xcol + 1];
        const float x2 = xs[b * (GTILE * ARITY) + xcol + 2];

        // hat basis per dim over grid {-1,0,+1}: d=0 -> relu(-x), 1 -> 1-|x|, 2 -> relu(x)
        const float w0[3] = { fmaxf(-x0, 0.0f), 1.0f - fabsf(x0), fmaxf(x0, 0.0f) };
        const float w1[3] = { fmaxf(-x1, 0.0f), 1.0f - fabsf(x1), fmaxf(x1, 0.0f) };
        const float w2[3] = { fmaxf(-x2, 0.0f), 1.0f - fabsf(x2), fmaxf(x2, 0.0f) };

        float4 acc = make_float4(0.0f, 0.0f, 0.0f, 0.0f);
        #pragma unroll
        for (int d2 = 0; d2 < 3; ++d2) {
            #pragma unroll
            for (int d1 = 0; d1 < 3; ++d1) {
                const float m = w2[d2] * w1[d1];
                #pragma unroll
                for (int d0 = 0; d0 < 3; ++d0) {
                    const float bs = m * w0[d0];            // basis[v], v = d0 + 3*d1 + 9*d2
                    const float4 pv = p[d0 + 3 * d1 + 9 * d2];
                    acc.x = fmaf(bs, pv.x, acc.x);
                    acc.y = fmaf(bs, pv.y, acc.y);
                    acc.z = fmaf(bs, pv.z, acc.z);
                    acc.w = fmaf(bs, pv.w, acc.w);
                }
            }
        }

        *reinterpret_cast<float4*>(out_base + (size_t)b * OCOLS) = acc;
    }
}

extern "C" void kernel_launch(void* const* d_in, const int* in_sizes, int n_in,
                              void* d_out, int out_size, void* d_ws, size_t ws_size,
                              hipStream_t stream) {
    const float* X = (const float*)d_in[0];   // [8192, 1536] f32
    const float* P = (const float*)d_in[1];   // [512, 27, 16] f32
    float* out = (float*)d_out;               // [8192, 8192] f32

    dim3 grid(BATCH / BTILE, GROUPS / GTILE); // 128 x 8
    dim3 block(256);
    lattice_interp_kernel<<<grid, block, 0, stream>>>(X, P, out);
}

// Round 2
// 91.626 us; speedup vs baseline: 1.2833x; 1.2833x over previous
//
#include <hip/hip_runtime.h>

// Problem constants (fixed by the reference)
#define BATCH   8192
#define GROUPS  512
#define ARITY   3
#define OUT_DIM 16
#define NV      27          // 3^3 vertices
#define XCOLS   (GROUPS*ARITY)      // 1536
#define OCOLS   (GROUPS*OUT_DIM)    // 8192

// Tiling: block = 256 threads = 4 waves.
//   wave w handles 16 groups; lane = (g_local<<2)|oq computes out[., g*16 + oq*4 .. +4)
//   block covers 64 groups (blockIdx.y) x 32 batches (blockIdx.x)
// BTILE=32 (was 64): LDS 24 KiB (not the occupancy limiter), 2048 blocks
// = 8/CU over ~3 resident -> tail quantization ~12% instead of ~50%.
#define BTILE 32
#define GTILE 64

__global__ __launch_bounds__(256, 3) void lattice_interp_kernel(
    const float* __restrict__ X,
    const float* __restrict__ P,
    float* __restrict__ out)
{
    __shared__ float xs[BTILE * GTILE * ARITY];   // 32*192 floats = 24 KiB, linear

    const int t  = threadIdx.x;
    const int b0 = blockIdx.x * BTILE;
    const int gb = blockIdx.y * GTILE;

    // ---- stage X tile rows [b0,b0+32) cols [gb*3, gb*3+192) into LDS.
    // flat float4 index f = t + k*256 ; r = f/48, c = f%48 ;
    // LDS dest offset = f*16B  (linear => matches global_load_lds lane layout)
    {
        const float* src_base = X + (size_t)b0 * XCOLS + gb * ARITY;
        #pragma unroll
        for (int k = 0; k < 6; ++k) {
            const int f = t + k * 256;
            const int r = f / 48;
            const int c = f % 48;
            const float* src = src_base + (size_t)r * XCOLS + c * 4;
            __builtin_amdgcn_global_load_lds(
                (const __attribute__((address_space(1))) void*)src,
                (__attribute__((address_space(3))) void*)&xs[f * 4],
                16, 0, 0);
        }
    }

    // ---- load this lane's param slice into registers (27 x float4), reused
    // for all 32 batches: no per-batch param traffic.
    const int wave = t >> 6;
    const int lane = t & 63;
    const int gl   = wave * 16 + (lane >> 2);   // group-local within block, 0..63
    const int oq   = lane & 3;                  // which float4 of the 16 outputs
    const int g    = gb + gl;

    float4 p[NV];
    {
        const float4* P4 = reinterpret_cast<const float4*>(P) + (size_t)g * (NV * 4) + oq;
        #pragma unroll
        for (int v = 0; v < NV; ++v) p[v] = P4[v * 4];
    }

    __syncthreads();   // drains the global_load_lds (compiler emits vmcnt(0))

    // ---- batch loop: all lanes of a wave share b; stores are one contiguous
    // 1 KiB segment per wave per b (lane l -> base + 4*l floats).
    const int xcol = gl * ARITY;
    float* out_base = out + (size_t)b0 * OCOLS + gb * OUT_DIM + t * 4;

    // software prefetch of next iteration's x triple hides ds_read latency
    float nx0 = xs[xcol + 0];
    float nx1 = xs[xcol + 1];
    float nx2 = xs[xcol + 2];

    #pragma unroll 1
    for (int b = 0; b < BTILE; ++b) {
        const float x0 = nx0;
        const float x1 = nx1;
        const float x2 = nx2;
        if (b < BTILE - 1) {
            const int nbase = (b + 1) * (GTILE * ARITY) + xcol;
            nx0 = xs[nbase + 0];
            nx1 = xs[nbase + 1];
            nx2 = xs[nbase + 2];
        }

        // hat basis per dim over grid {-1,0,+1}: d=0 -> relu(-x), 1 -> 1-|x|, 2 -> relu(x)
        const float w0[3] = { fmaxf(-x0, 0.0f), 1.0f - fabsf(x0), fmaxf(x0, 0.0f) };
        const float w1[3] = { fmaxf(-x1, 0.0f), 1.0f - fabsf(x1), fmaxf(x1, 0.0f) };
        const float w2[3] = { fmaxf(-x2, 0.0f), 1.0f - fabsf(x2), fmaxf(x2, 0.0f) };

        float4 acc = make_float4(0.0f, 0.0f, 0.0f, 0.0f);
        #pragma unroll
        for (int d2 = 0; d2 < 3; ++d2) {
            #pragma unroll
            for (int d1 = 0; d1 < 3; ++d1) {
                const float m = w2[d2] * w1[d1];
                #pragma unroll
                for (int d0 = 0; d0 < 3; ++d0) {
                    const float bs = m * w0[d0];            // basis[v], v = d0 + 3*d1 + 9*d2
                    const float4 pv = p[d0 + 3 * d1 + 9 * d2];
                    acc.x = fmaf(bs, pv.x, acc.x);
                    acc.y = fmaf(bs, pv.y, acc.y);
                    acc.z = fmaf(bs, pv.z, acc.z);
                    acc.w = fmaf(bs, pv.w, acc.w);
                }
            }
        }

        *reinterpret_cast<float4*>(out_base + (size_t)b * OCOLS) = acc;
    }
}

extern "C" void kernel_launch(void* const* d_in, const int* in_sizes, int n_in,
                              void* d_out, int out_size, void* d_ws, size_t ws_size,
                              hipStream_t stream) {
    const float* X = (const float*)d_in[0];   // [8192, 1536] f32
    const float* P = (const float*)d_in[1];   // [512, 27, 16] f32
    float* out = (float*)d_out;               // [8192, 8192] f32

    dim3 grid(BATCH / BTILE, GROUPS / GTILE); // 256 x 8
    dim3 block(256);
    lattice_interp_kernel<<<grid, block, 0, stream>>>(X, P, out);
}

// Round 3
// 78.716 us; speedup vs baseline: 1.4938x; 1.1640x over previous
//
#include <hip/hip_runtime.h>

// Problem constants (fixed by the reference)
#define BATCH   8192
#define GROUPS  512
#define ARITY   3
#define OUT_DIM 16
#define NV      27          // 3^3 vertices
#define XCOLS   (GROUPS*ARITY)      // 1536
#define OCOLS   (GROUPS*OUT_DIM)    // 8192

// Tiling: block = 256 threads = 4 waves.
//   lane covers (group gl = t>>3, output-half oh = t&7): 2 floats of the 16.
//   block covers 32 groups (blockIdx.y) x 64 batches (blockIdx.x).
// float2 lanes: p[27] = 54 VGPR (vs 108 as float4) -> ~5 waves/SIMD resident.
#define BTILE 64
#define GTILE 32

typedef float f32x2 __attribute__((ext_vector_type(2)));

__global__ __launch_bounds__(256, 4) void lattice_interp_kernel(
    const float* __restrict__ X,
    const float* __restrict__ P,
    float* __restrict__ out)
{
    __shared__ float xs[BTILE * GTILE * ARITY];   // 64*96 floats = 24 KiB, linear

    const int t  = threadIdx.x;
    const int b0 = blockIdx.x * BTILE;
    const int gb = blockIdx.y * GTILE;

    // ---- stage X tile rows [b0,b0+64) cols [gb*3, gb*3+96) into LDS.
    // flat float4 index f = t + k*256 ; r = f/24, c = f%24 ;
    // LDS dest = f*16B (linear => matches global_load_lds wave-uniform+lane*16)
    {
        const float* src_base = X + (size_t)b0 * XCOLS + gb * ARITY;
        #pragma unroll
        for (int k = 0; k < 6; ++k) {
            const int f = t + k * 256;
            const int r = f / 24;
            const int c = f % 24;
            const float* src = src_base + (size_t)r * XCOLS + c * 4;
            __builtin_amdgcn_global_load_lds(
                (const __attribute__((address_space(1))) void*)src,
                (__attribute__((address_space(3))) void*)&xs[f * 4],
                16, 0, 0);
        }
    }

    // ---- this lane's param slice: 27 x float2 (54 VGPR), reused for all 64 b.
    const int gl = t >> 3;     // group-local 0..31
    const int oh = t & 7;      // which float2 of the 16 outputs
    const int g  = gb + gl;

    f32x2 p[NV];
    {
        const f32x2* P2 = reinterpret_cast<const f32x2*>(P) + (size_t)g * (NV * 8) + oh;
        #pragma unroll
        for (int v = 0; v < NV; ++v) p[v] = P2[v * 8];
    }

    __syncthreads();   // drains global_load_lds

    // compute-read banks: 8 lanes/group broadcast one addr; 8 addrs stride 3
    // floats -> banks {0,3,..,21}, conflict-free.
    const int xcol = gl * ARITY;
    // out col within block = gl*16 + oh*2 == 2*t  -> wave writes 512 contiguous B
    float* outp = out + (size_t)b0 * OCOLS + gb * OUT_DIM + t * 2;

    #pragma unroll 2
    for (int b = 0; b < BTILE; ++b) {
        const float x0 = xs[b * (GTILE * ARITY) + xcol + 0];
        const float x1 = xs[b * (GTILE * ARITY) + xcol + 1];
        const float x2 = xs[b * (GTILE * ARITY) + xcol + 2];

        // hat basis over {-1,0,+1}: d=0 -> relu(-x), 1 -> 1-|x|, 2 -> relu(x)
        const float w0a[3] = { fmaxf(-x0, 0.0f), 1.0f - fabsf(x0), fmaxf(x0, 0.0f) };
        const float w1a[3] = { fmaxf(-x1, 0.0f), 1.0f - fabsf(x1), fmaxf(x1, 0.0f) };
        const float w2a[3] = { fmaxf(-x2, 0.0f), 1.0f - fabsf(x2), fmaxf(x2, 0.0f) };

        // factorized tensor-product contraction (exact same math, fewer ops):
        // B1[i]=sum_d0 w0[d0]*p[3i+d0]; B2[d2]=sum_d1 w1[d1]*B1[d1+3d2];
        // acc = sum_d2 w2[d2]*B2[d2].   v = d0 + 3*d1 + 9*d2 = 3*i + d0.
        f32x2 acc = { 0.0f, 0.0f };
        #pragma unroll
        for (int d2 = 0; d2 < 3; ++d2) {
            f32x2 b2 = { 0.0f, 0.0f };
            #pragma unroll
            for (int d1 = 0; d1 < 3; ++d1) {
                const int i = d1 + 3 * d2;
                f32x2 b1 = w0a[0] * p[3*i] + w0a[1] * p[3*i+1] + w0a[2] * p[3*i+2];
                b2 += w1a[d1] * b1;
            }
            acc += w2a[d2] * b2;
        }

        __builtin_nontemporal_store(acc, reinterpret_cast<f32x2*>(outp + (size_t)b * OCOLS));
    }
}

extern "C" void kernel_launch(void* const* d_in, const int* in_sizes, int n_in,
                              void* d_out, int out_size, void* d_ws, size_t ws_size,
                              hipStream_t stream) {
    const float* X = (const float*)d_in[0];   // [8192, 1536] f32
    const float* P = (const float*)d_in[1];   // [512, 27, 16] f32
    float* out = (float*)d_out;               // [8192, 8192] f32

    dim3 grid(BATCH / BTILE, GROUPS / GTILE); // 128 x 16
    dim3 block(256);
    lattice_interp_kernel<<<grid, block, 0, stream>>>(X, P, out);
}